// Round 12
// baseline (917.801 us; speedup 1.0000x reference)
//
#include <hip/hip_runtime.h>
#include <hip/hip_bf16.h>
#include <math.h>

// Problem constants
constexpr int B    = 16;
constexpr int H    = 96;
constexpr int W    = 96;
constexpr int C    = 512;
constexpr int D    = 64;
constexpr int NBH  = 24;          // blocks per side
constexpr int NB   = 576;         // num_block_tot
constexpr int HW   = 9216;
constexpr int TOPK = 16;
constexpr int TK2  = 32;          // 2*TOPK
constexpr int NCAND = 40;         // selection threshold rank (exact fp32 re-rank after)
constexpr int CAP  = 64;          // candidate cap (ties)
constexpr int SP   = 516;         // embed LDS row pad (px-addresses bank-distinct)
constexpr int TP   = 68;          // scores LDS row pad (16B-aligned, 2-way max)

// ---------------------------------------------------------------- K0: transpose weights
__global__ void k_transpose(const float* __restrict__ Wk, const float* __restrict__ Wq,
                            float* __restrict__ WkT, float* __restrict__ WqT) {
    int idx = blockIdx.x * 256 + threadIdx.x;   // over C*D
    if (idx < C * D) {
        int c = idx >> 6, d = idx & 63;
        WkT[c * D + d] = Wk[d * C + c];
        WqT[c * D + d] = Wq[d * C + c];
    }
}

// ---------------------------------------------------------------- K1: pool + k (fp32, frozen numerics)
// One block per (b, n) 4x4 block. Thread = (px = t>>4, dg = t&15) -> 1 px x 4 d.
// Per cc-quad: 1 uniform ds_read_b128 (x) + 4 coalesced b128 WkT + 16 fmaf.
// NUMERICS FROZEN: asc-c fmaf chain per (px,d) split at c=384; k=(a+e)+bk;
// mean sequential (dy,dx) then *0.0625f.
__global__ __launch_bounds__(256, 4) void k_embed(
    const float* __restrict__ src,
    const float* __restrict__ WkT, const float* __restrict__ bk,
    float* __restrict__ k32, float* __restrict__ emb) {
    __shared__ float sS[16 * SP];   // 33 KB

    int t   = threadIdx.x;
    int blk = blockIdx.x;
    int b = blk / NB, n = blk % NB;
    int nh = n / NBH, nw = n % NBH;
    int y0 = nh * 4, x0 = nw * 4;

    // stage 16 px rows (coalesced float4)
    #pragma unroll
    for (int r = 0; r < 8; ++r) {
        int f4 = r * 256 + t;
        int px = f4 >> 7, c4 = f4 & 127;
        int dy = px >> 2, dx = px & 3;
        *(float4*)&sS[px * SP + c4 * 4] =
            *(const float4*)&src[((size_t)(b * H + y0 + dy) * W + (x0 + dx)) * C + c4 * 4];
    }
    __syncthreads();

    // block mean -> emb (frozen sequential (dy,dx) order), coalesced LDS columns
    #pragma unroll
    for (int s = 0; s < 2; ++s) {
        int cc = s * 256 + t;
        float sum = sS[cc];
        #pragma unroll
        for (int px = 1; px < 16; ++px) sum += sS[px * SP + cc];
        emb[((size_t)b * NB + n) * C + cc] = sum * 0.0625f;
    }

    // k chains
    int px = t >> 4, dg = t & 15;
    const float* sx = &sS[px * SP];
    const float* wb = WkT + dg * 4;

    float a[4] = {0.f, 0.f, 0.f, 0.f};
    float e[4] = {0.f, 0.f, 0.f, 0.f};

    #pragma unroll 2
    for (int cg = 0; cg < 96; ++cg) {       // c < 384: panel a
        float4 xv = *(const float4*)&sx[cg * 4];       // uniform per px-group
        float4 w0 = *(const float4*)&wb[(cg * 4 + 0) * D];
        float4 w1 = *(const float4*)&wb[(cg * 4 + 1) * D];
        float4 w2 = *(const float4*)&wb[(cg * 4 + 2) * D];
        float4 w3 = *(const float4*)&wb[(cg * 4 + 3) * D];
        const float* xf = (const float*)&xv;
        const float* wf[4] = {(const float*)&w0, (const float*)&w1,
                              (const float*)&w2, (const float*)&w3};
        #pragma unroll
        for (int j = 0; j < 4; ++j)         // ascending c: frozen chain order
            #pragma unroll
            for (int jj = 0; jj < 4; ++jj)
                a[jj] = __builtin_fmaf(xf[j], wf[j][jj], a[jj]);
    }
    #pragma unroll 2
    for (int cg = 96; cg < 128; ++cg) {     // c >= 384: panel e
        float4 xv = *(const float4*)&sx[cg * 4];
        float4 w0 = *(const float4*)&wb[(cg * 4 + 0) * D];
        float4 w1 = *(const float4*)&wb[(cg * 4 + 1) * D];
        float4 w2 = *(const float4*)&wb[(cg * 4 + 2) * D];
        float4 w3 = *(const float4*)&wb[(cg * 4 + 3) * D];
        const float* xf = (const float*)&xv;
        const float* wf[4] = {(const float*)&w0, (const float*)&w1,
                              (const float*)&w2, (const float*)&w3};
        #pragma unroll
        for (int j = 0; j < 4; ++j)
            #pragma unroll
            for (int jj = 0; jj < 4; ++jj)
                e[jj] = __builtin_fmaf(xf[j], wf[j][jj], e[jj]);
    }

    float4 bk4 = *(const float4*)&bk[dg * 4];
    const float* bkf = (const float*)&bk4;
    int dy = px >> 2, dx = px & 3;
    size_t p = (size_t)(y0 + dy) * W + (x0 + dx);
    float4 o;
    ((float*)&o)[0] = (a[0] + e[0]) + bkf[0];
    ((float*)&o)[1] = (a[1] + e[1]) + bkf[1];
    ((float*)&o)[2] = (a[2] + e[2]) + bkf[2];
    ((float*)&o)[3] = (a[3] + e[3]) + bkf[3];
    *(float4*)&k32[((size_t)b * HW + p) * D + dg * 4] = o;
}

// ---------------------------------------------------------------- K1b: q from emb (frozen chain)
// 576 blocks x 16 rows; wave ng -> rows r0..r0+3 (ILP-4). emb uniform b128, WqT coalesced b32.
__global__ __launch_bounds__(256) void k_q(
    const float* __restrict__ emb, const float* __restrict__ WqT,
    const float* __restrict__ bq, float* __restrict__ q32) {
    int t  = threadIdx.x;
    int d  = t & 63;
    int ng = t >> 6;
    int r0 = blockIdx.x * 16 + ng * 4;
    const float* e0 = emb + (size_t)(r0 + 0) * C;
    const float* e1 = emb + (size_t)(r0 + 1) * C;
    const float* e2 = emb + (size_t)(r0 + 2) * C;
    const float* e3 = emb + (size_t)(r0 + 3) * C;

    float qa0 = 0.f, qa1 = 0.f, qa2 = 0.f, qa3 = 0.f;
    float qe0 = 0.f, qe1 = 0.f, qe2 = 0.f, qe3 = 0.f;
    #pragma unroll 2
    for (int cg = 0; cg < 96; ++cg) {
        float4 v0 = *(const float4*)&e0[cg * 4];
        float4 v1 = *(const float4*)&e1[cg * 4];
        float4 v2 = *(const float4*)&e2[cg * 4];
        float4 v3 = *(const float4*)&e3[cg * 4];
        float w0 = WqT[(cg * 4 + 0) * D + d];
        float w1 = WqT[(cg * 4 + 1) * D + d];
        float w2 = WqT[(cg * 4 + 2) * D + d];
        float w3 = WqT[(cg * 4 + 3) * D + d];
        const float* f0 = (const float*)&v0;
        const float* f1 = (const float*)&v1;
        const float* f2 = (const float*)&v2;
        const float* f3 = (const float*)&v3;
        float wj[4] = {w0, w1, w2, w3};
        #pragma unroll
        for (int j = 0; j < 4; ++j) {
            qa0 = __builtin_fmaf(f0[j], wj[j], qa0);
            qa1 = __builtin_fmaf(f1[j], wj[j], qa1);
            qa2 = __builtin_fmaf(f2[j], wj[j], qa2);
            qa3 = __builtin_fmaf(f3[j], wj[j], qa3);
        }
    }
    #pragma unroll 2
    for (int cg = 96; cg < 128; ++cg) {
        float4 v0 = *(const float4*)&e0[cg * 4];
        float4 v1 = *(const float4*)&e1[cg * 4];
        float4 v2 = *(const float4*)&e2[cg * 4];
        float4 v3 = *(const float4*)&e3[cg * 4];
        float w0 = WqT[(cg * 4 + 0) * D + d];
        float w1 = WqT[(cg * 4 + 1) * D + d];
        float w2 = WqT[(cg * 4 + 2) * D + d];
        float w3 = WqT[(cg * 4 + 3) * D + d];
        const float* f0 = (const float*)&v0;
        const float* f1 = (const float*)&v1;
        const float* f2 = (const float*)&v2;
        const float* f3 = (const float*)&v3;
        float wj[4] = {w0, w1, w2, w3};
        #pragma unroll
        for (int j = 0; j < 4; ++j) {
            qe0 = __builtin_fmaf(f0[j], wj[j], qe0);
            qe1 = __builtin_fmaf(f1[j], wj[j], qe1);
            qe2 = __builtin_fmaf(f2[j], wj[j], qe2);
            qe3 = __builtin_fmaf(f3[j], wj[j], qe3);
        }
    }
    float bqd = bq[d];
    q32[(size_t)(r0 + 0) * D + d] = (qa0 + qe0) + bqd;
    q32[(size_t)(r0 + 1) * D + d] = (qa1 + qe1) + bqd;
    q32[(size_t)(r0 + 2) * D + d] = (qa2 + qe2) + bqd;
    q32[(size_t)(r0 + 3) * D + d] = (qa3 + qe3) + bqd;
}

// ---------------------------------------------------------------- K2: scores SHADOW (fp16) — numerics free
// v3: 64x64 tile, 4x4 micro, d-major transposed LDS (pad 68). Per d: 2 ds_read_b128 + 16 fmaf.
__global__ __launch_bounds__(256, 4) void k_scores(
    const float* __restrict__ q32, const float* __restrict__ k32,
    _Float16* __restrict__ S16) {
    __shared__ float sQT[D * TP];   // [d][row], 17.4 KB
    __shared__ float sKT[D * TP];

    int t  = threadIdx.x;
    int p0 = blockIdx.x * 64;      // 144 tiles
    int n0 = blockIdx.y * 64;      // 9 tiles
    int b  = blockIdx.z;
    int tx = t & 15, ty = t >> 4;

    const float* qb = q32 + ((size_t)b * NB + n0) * D;
    const float* kb = k32 + ((size_t)b * HW + p0) * D;

    // stage + transpose: linear f4 idx -> (row, d4); write 4 scalars to [d][row]
    #pragma unroll
    for (int r = 0; r < 4; ++r) {
        int L = r * 256 + t;
        int row = L >> 4, c4 = L & 15;
        float4 vq = *(const float4*)&qb[(size_t)row * D + c4 * 4];
        float4 vk = *(const float4*)&kb[(size_t)row * D + c4 * 4];
        const float* fq = (const float*)&vq;
        const float* fk = (const float*)&vk;
        #pragma unroll
        for (int i = 0; i < 4; ++i) {
            sQT[(c4 * 4 + i) * TP + row] = fq[i];
            sKT[(c4 * 4 + i) * TP + row] = fk[i];
        }
    }
    __syncthreads();

    float acc[4][4] = {};
    #pragma unroll 2
    for (int d = 0; d < D; ++d) {
        float4 qv = *(const float4*)&sQT[d * TP + 4 * ty];
        float4 kv = *(const float4*)&sKT[d * TP + 4 * tx];
        const float* qf = (const float*)&qv;
        const float* kf = (const float*)&kv;
        #pragma unroll
        for (int i = 0; i < 4; ++i)
            #pragma unroll
            for (int j = 0; j < 4; ++j)
                acc[i][j] = __builtin_fmaf(qf[i], kf[j], acc[i][j]);
    }

    _Float16* Sb = S16 + (size_t)b * NB * HW;
    #pragma unroll
    for (int i = 0; i < 4; ++i) {
        int nrow = n0 + 4 * ty + i;
        _Float16 h0 = (_Float16)acc[i][0];
        _Float16 h1 = (_Float16)acc[i][1];
        _Float16 h2 = (_Float16)acc[i][2];
        _Float16 h3 = (_Float16)acc[i][3];
        uint2 pack;
        pack.x = ((unsigned int)*(unsigned short*)&h1 << 16) | (unsigned int)*(unsigned short*)&h0;
        pack.y = ((unsigned int)*(unsigned short*)&h3 << 16) | (unsigned int)*(unsigned short*)&h2;
        *(uint2*)&Sb[(size_t)nrow * HW + (p0 + 4 * tx)] = pack;
    }
}

// ---------------------------------------------------------------- K3: per-row top-k via 2-pass radix select
__global__ __launch_bounds__(256) void k_topk(
    const _Float16* __restrict__ S16,
    const float* __restrict__ q32, const float* __restrict__ k32,
    int* __restrict__ cidx, float* __restrict__ cval, double* __restrict__ rowss) {
    __shared__ int    hist[4][256];   // per-wave sub-histograms
    __shared__ int    sfx[256];
    __shared__ int    b0s, mAbove, thrS, gcnt;
    __shared__ int    cps[CAP];
    __shared__ float  cv[CAP];
    __shared__ int    cp[CAP];
    __shared__ float  sv[CAP];
    __shared__ int    sp[CAP];
    __shared__ double ssq[TOPK];

    int t   = threadIdx.x;
    int row = blockIdx.x;            // b*NB + n
    int b = row / NB, n = row % NB;
    int wid = t >> 6;

    #pragma unroll
    for (int w = 0; w < 4; ++w) hist[w][t] = 0;
    if (t == 0) gcnt = 0;
    __syncthreads();

    const unsigned short* Srow = (const unsigned short*)(S16 + (size_t)row * HW);
    unsigned int my[36];
    #pragma unroll
    for (int c = 0; c < 9; ++c) {
        ushort4 v4 = ((const ushort4*)Srow)[c * 256 + t];
        #pragma unroll
        for (int j = 0; j < 4; ++j) {
            unsigned int h = (j == 0 ? v4.x : j == 1 ? v4.y : j == 2 ? v4.z : v4.w);
            unsigned int m = (h & 0x8000u) ? (h ^ 0xFFFFu) : (h | 0x8000u);
            int p = (c * 256 + t) * 4 + j;
            int hh = p / W, ww = p - hh * W;
            if (((hh >> 2) * NBH + (ww >> 2)) == n) m = 0;   // self-block mask
            my[c * 4 + j] = m;
            atomicAdd(&hist[wid][m >> 8], 1);
        }
    }
    __syncthreads();

    sfx[t] = hist[0][t] + hist[1][t] + hist[2][t] + hist[3][t];
    __syncthreads();
    #pragma unroll
    for (int off = 1; off < 256; off <<= 1) {
        int v = (t + off < 256) ? sfx[t + off] : 0;
        __syncthreads();
        sfx[t] += v;
        __syncthreads();
    }
    if (sfx[t] >= NCAND && (t == 255 || sfx[t + 1] < NCAND)) {
        b0s = t; mAbove = (t == 255) ? 0 : sfx[t + 1];
    }
    __syncthreads();
    int b0 = b0s, mab = mAbove;
    __syncthreads();

    #pragma unroll
    for (int w = 0; w < 4; ++w) hist[w][t] = 0;
    __syncthreads();
    #pragma unroll
    for (int i = 0; i < 36; ++i)
        if ((int)(my[i] >> 8) == b0) atomicAdd(&hist[wid][my[i] & 255u], 1);
    __syncthreads();
    sfx[t] = hist[0][t] + hist[1][t] + hist[2][t] + hist[3][t];
    __syncthreads();
    #pragma unroll
    for (int off = 1; off < 256; off <<= 1) {
        int v = (t + off < 256) ? sfx[t + off] : 0;
        __syncthreads();
        sfx[t] += v;
        __syncthreads();
    }
    if (mab + sfx[t] >= NCAND && (t == 255 || mab + sfx[t + 1] < NCAND))
        thrS = (b0 << 8) | t;
    __syncthreads();
    unsigned int thr = (unsigned int)thrS;

    #pragma unroll
    for (int i = 0; i < 36; ++i) {
        if (my[i] >= thr) {
            int pos = atomicAdd(&gcnt, 1);
            if (pos < CAP) {
                int c = i >> 2, j = i & 3;
                cps[pos] = (c * 256 + t) * 4 + j;
            }
        }
    }
    __syncthreads();
    int M = min(gcnt, CAP);

    // exact fp32 re-rank — np.einsum SSE order, no FMA (NUMERICS FROZEN)
    if (t < M) {
        #pragma clang fp contract(off)
        int p = cps[t];
        const float* qr = q32 + (size_t)row * D;
        const float* kr = k32 + ((size_t)b * HW + p) * D;
        float L0 = 0.f, L1 = 0.f, L2 = 0.f, L3 = 0.f;
        #pragma unroll
        for (int j = 0; j < 16; ++j) {
            L0 = L0 + qr[4 * j + 0] * kr[4 * j + 0];
            L1 = L1 + qr[4 * j + 1] * kr[4 * j + 1];
            L2 = L2 + qr[4 * j + 2] * kr[4 * j + 2];
            L3 = L3 + qr[4 * j + 3] * kr[4 * j + 3];
        }
        cv[t] = (L0 + L1) + (L2 + L3);
        cp[t] = p;
    }
    __syncthreads();

    if (t < M) {
        float v = cv[t]; int p = cp[t];
        int rank = 0;
        for (int j = 0; j < M; ++j) {
            float vj = cv[j];
            rank += (vj > v) || (vj == v && cp[j] < p);
        }
        sv[rank] = v; sp[rank] = p;
    }
    __syncthreads();

    if (t < TK2) {
        cval[(size_t)row * TK2 + t] = sv[t];
        cidx[(size_t)row * TK2 + t] = sp[t];
    }
    if (t < TOPK) {
        double vi = (double)sv[t], s = 0.0;
        #pragma unroll
        for (int j = 0; j < TK2; ++j) { double dd = vi - (double)sv[j]; s += dd * dd; }
        ssq[t] = s;
    }
    __syncthreads();
    if (t == 0) {
        double s = 0.0;
        #pragma unroll
        for (int i = 0; i < TOPK; ++i) s += ssq[i];
        rowss[row] = s;
    }
}

// ---------------------------------------------------------------- K4: per-batch RMS -> scale
__global__ void k_rms(const double* __restrict__ rowss, double* __restrict__ scale) {
    __shared__ double sb[256];
    int b = blockIdx.x, t = threadIdx.x;
    double s = 0.0;
    for (int r = t; r < NB; r += 256) s += rowss[b * NB + r];
    sb[t] = s; __syncthreads();
    for (int st = 128; st > 0; st >>= 1) {
        if (t < st) sb[t] += sb[t + st];
        __syncthreads();
    }
    if (t == 0) {
        double rms = sqrt(sb[0] / ((double)NB * TOPK * TK2));
        scale[b] = 10.0 / (rms + 1e-3);
    }
}

// ---------------------------------------------------------------- K5: finalize — SOLE writer of d_out (float32)
__global__ __launch_bounds__(256) void k_final(
    const int* __restrict__ cidx, const float* __restrict__ cval,
    const double* __restrict__ scale, float* __restrict__ out) {
    __shared__ double sv[16][TK2];
    int t = threadIdx.x;
    int row0 = blockIdx.x * 16;
    for (int idx = t; idx < 16 * TK2; idx += 256) {
        int r = idx >> 5, j = idx & 31;
        sv[r][j] = (double)cval[(size_t)(row0 + r) * TK2 + j];
    }
    __syncthreads();
    int r = t >> 4, i = t & 15;
    int row = row0 + r;
    double scb = scale[row / NB];
    double vi = sv[r][i];
    double s = 0.0;
    #pragma unroll
    for (int j = 0; j < TK2; ++j) {
        double x = (vi - sv[r][j]) * scb;
        s += 1.0 / (1.0 + exp(-x));
    }
    out[(size_t)B * NB * TOPK + (size_t)row * TOPK + i] = (float)tanh(s - (double)TOPK);
    out[(size_t)row * TOPK + i] = (float)cidx[(size_t)row * TK2 + i];
}

// ---------------------------------------------------------------- sentinel fill (ws too small)
__global__ void k_fill(float* out, int nelem) {
    int i = blockIdx.x * 256 + threadIdx.x;
    if (i < nelem) out[i] = -12345.0f;
}

// ---------------------------------------------------------------- launch
extern "C" void kernel_launch(void* const* d_in, const int* in_sizes, int n_in,
                              void* d_out, int out_size, void* d_ws, size_t ws_size,
                              hipStream_t stream) {
    const float* src = (const float*)d_in[0];
    const float* Wq  = (const float*)d_in[1];
    const float* bq  = (const float*)d_in[2];
    const float* Wk  = (const float*)d_in[3];
    const float* bk  = (const float*)d_in[4];
    float* out = (float*)d_out;

    char* ws = (char*)d_ws;
    size_t oWkT = 0;
    size_t oWqT = oWkT + (size_t)C * D * 4;
    size_t oQ   = oWqT + (size_t)C * D * 4;
    size_t oK   = oQ   + (size_t)B * NB * D * 4;
    size_t oS   = oK   + (size_t)B * HW * D * 4;
    size_t oEmb = oS   + (size_t)B * NB * HW * 2;
    size_t oCV  = oEmb + (size_t)B * NB * C * 4;
    size_t oCI  = oCV  + (size_t)B * NB * TK2 * 4;
    size_t oRS  = oCI  + (size_t)B * NB * TK2 * 4;
    size_t oSc  = oRS  + (size_t)B * NB * 8;
    size_t need = oSc  + (size_t)B * 8;

    if (ws_size < need) {
        k_fill<<<(out_size + 255) / 256, 256, 0, stream>>>(out, out_size);
        return;
    }

    float*     WkT  = (float*)(ws + oWkT);
    float*     WqT  = (float*)(ws + oWqT);
    float*     q32  = (float*)(ws + oQ);
    float*     k32  = (float*)(ws + oK);
    _Float16*  S16  = (_Float16*)(ws + oS);
    float*     emb  = (float*)(ws + oEmb);
    float*     cval = (float*)(ws + oCV);
    int*       cidx = (int*)(ws + oCI);
    double*    rss  = (double*)(ws + oRS);
    double*    scl  = (double*)(ws + oSc);

    k_transpose<<<(C * D + 255) / 256, 256, 0, stream>>>(Wk, Wq, WkT, WqT);
    k_embed<<<B * NB, 256, 0, stream>>>(src, WkT, bk, k32, emb);
    k_q<<<B * NB / 16, 256, 0, stream>>>(emb, WqT, bq, q32);
    k_scores<<<dim3(HW / 64, NB / 64, B), 256, 0, stream>>>(q32, k32, S16);
    k_topk<<<B * NB, 256, 0, stream>>>(S16, q32, k32, cidx, cval, rss);
    k_rms<<<B, 256, 0, stream>>>(rss, scl);
    k_final<<<B * NB / 16, 256, 0, stream>>>(cidx, cval, scl, out);
}

// Round 13
// 479.657 us; speedup vs baseline: 1.9135x; 1.9135x over previous
//
#include <hip/hip_runtime.h>
#include <hip/hip_bf16.h>
#include <math.h>

// Problem constants
constexpr int B    = 16;
constexpr int H    = 96;
constexpr int W    = 96;
constexpr int C    = 512;
constexpr int D    = 64;
constexpr int NBH  = 24;          // blocks per side
constexpr int NB   = 576;         // num_block_tot
constexpr int HW   = 9216;
constexpr int TOPK = 16;
constexpr int TK2  = 32;          // 2*TOPK
constexpr int NCAND = 40;         // selection threshold rank (exact fp32 re-rank after)
constexpr int CAP  = 64;          // candidate cap (ties)

typedef __attribute__((ext_vector_type(8))) short bf16x8;
typedef __attribute__((ext_vector_type(4))) float f32x4;

__device__ inline unsigned short f2bf(float x) {   // fp32 -> bf16 RNE
    unsigned int u = __float_as_uint(x);
    return (unsigned short)((u + 0x7FFFu + ((u >> 16) & 1u)) >> 16);
}

// ---------------------------------------------------------------- K0: transpose weights
__global__ void k_transpose(const float* __restrict__ Wk, const float* __restrict__ Wq,
                            float* __restrict__ WkT, float* __restrict__ WqT) {
    int idx = blockIdx.x * 256 + threadIdx.x;   // over C*D
    if (idx < C * D) {
        int c = idx >> 6, d = idx & 63;
        WkT[c * D + d] = Wk[d * C + c];
        WqT[c * D + d] = Wq[d * C + c];
    }
}

// ---------------------------------------------------------------- K1: pool + k (R11 verbatim — known 272 us, VALU 73%)
// NUMERICS FROZEN: asc-c fmaf chain split at c=384; k=(a+e)+bk; mean sequential (dy,dx) * 0.0625f.
__global__ __launch_bounds__(256, 4) void k_embed(
    const float* __restrict__ src,
    const float* __restrict__ WkT, const float* __restrict__ bk,
    float* __restrict__ k32, float* __restrict__ emb) {
    __shared__ float sS[16][C];    // 32 KB

    int t   = threadIdx.x;
    int blk = blockIdx.x;
    int b = blk / NB, n = blk % NB;
    int nh = n / NBH, nw = n % NBH;
    int y0 = nh * 4, x0 = nw * 4;

    #pragma unroll
    for (int r = 0; r < 8; ++r) {
        int f4 = r * 256 + t;
        int px = f4 >> 7, c4 = f4 & 127;
        int dy = px >> 2, dx = px & 3;
        ((float4*)sS[px])[c4] =
            *(const float4*)&src[((size_t)(b * H + y0 + dy) * W + (x0 + dx)) * C + c4 * 4];
    }
    __syncthreads();

    #pragma unroll
    for (int s = 0; s < 2; ++s) {
        int cc = s * 256 + t;
        float sum = sS[0][cc];
        #pragma unroll
        for (int px = 1; px < 16; ++px) sum += sS[px][cc];
        emb[((size_t)b * NB + n) * C + cc] = sum * 0.0625f;
    }

    int d = t & 63, pg = t >> 6;
    const float* s0 = sS[pg * 4 + 0];
    const float* s1 = sS[pg * 4 + 1];
    const float* s2 = sS[pg * 4 + 2];
    const float* s3 = sS[pg * 4 + 3];

    float a0 = 0.f, a1 = 0.f, a2 = 0.f, a3 = 0.f;
    float e0 = 0.f, e1 = 0.f, e2 = 0.f, e3 = 0.f;

    #pragma unroll 2
    for (int cg = 0; cg < 96; ++cg) {
        float4 x0v = *(const float4*)&s0[cg * 4];
        float4 x1v = *(const float4*)&s1[cg * 4];
        float4 x2v = *(const float4*)&s2[cg * 4];
        float4 x3v = *(const float4*)&s3[cg * 4];
        float w0 = WkT[(cg * 4 + 0) * D + d];
        float w1 = WkT[(cg * 4 + 1) * D + d];
        float w2 = WkT[(cg * 4 + 2) * D + d];
        float w3 = WkT[(cg * 4 + 3) * D + d];
        const float* x0f = (const float*)&x0v;
        const float* x1f = (const float*)&x1v;
        const float* x2f = (const float*)&x2v;
        const float* x3f = (const float*)&x3v;
        float wj[4] = {w0, w1, w2, w3};
        #pragma unroll
        for (int j = 0; j < 4; ++j) {
            a0 = __builtin_fmaf(x0f[j], wj[j], a0);
            a1 = __builtin_fmaf(x1f[j], wj[j], a1);
            a2 = __builtin_fmaf(x2f[j], wj[j], a2);
            a3 = __builtin_fmaf(x3f[j], wj[j], a3);
        }
    }
    #pragma unroll 2
    for (int cg = 96; cg < 128; ++cg) {
        float4 x0v = *(const float4*)&s0[cg * 4];
        float4 x1v = *(const float4*)&s1[cg * 4];
        float4 x2v = *(const float4*)&s2[cg * 4];
        float4 x3v = *(const float4*)&s3[cg * 4];
        float w0 = WkT[(cg * 4 + 0) * D + d];
        float w1 = WkT[(cg * 4 + 1) * D + d];
        float w2 = WkT[(cg * 4 + 2) * D + d];
        float w3 = WkT[(cg * 4 + 3) * D + d];
        const float* x0f = (const float*)&x0v;
        const float* x1f = (const float*)&x1v;
        const float* x2f = (const float*)&x2v;
        const float* x3f = (const float*)&x3v;
        float wj[4] = {w0, w1, w2, w3};
        #pragma unroll
        for (int j = 0; j < 4; ++j) {
            e0 = __builtin_fmaf(x0f[j], wj[j], e0);
            e1 = __builtin_fmaf(x1f[j], wj[j], e1);
            e2 = __builtin_fmaf(x2f[j], wj[j], e2);
            e3 = __builtin_fmaf(x3f[j], wj[j], e3);
        }
    }

    float bkd = bk[d];
    #pragma unroll
    for (int u = 0; u < 4; ++u) {
        int pxx = pg * 4 + u;
        int dy = pxx >> 2, dx = pxx & 3;
        size_t p = (size_t)(y0 + dy) * W + (x0 + dx);
        float a = (u == 0 ? a0 : u == 1 ? a1 : u == 2 ? a2 : a3);
        float e = (u == 0 ? e0 : u == 1 ? e1 : u == 2 ? e2 : e3);
        k32[((size_t)b * HW + p) * D + d] = (a + e) + bkd;
    }
}

// ---------------------------------------------------------------- K1b: q from emb (frozen chain, R11)
__global__ __launch_bounds__(256) void k_q(
    const float* __restrict__ emb, const float* __restrict__ WqT,
    const float* __restrict__ bq, float* __restrict__ q32) {
    int t  = threadIdx.x;
    int d  = t & 63;
    int ng = t >> 6;
    int r0 = blockIdx.x * 16 + ng * 4;
    const float* e0 = emb + (size_t)(r0 + 0) * C;
    const float* e1 = emb + (size_t)(r0 + 1) * C;
    const float* e2 = emb + (size_t)(r0 + 2) * C;
    const float* e3 = emb + (size_t)(r0 + 3) * C;

    float qa0 = 0.f, qa1 = 0.f, qa2 = 0.f, qa3 = 0.f;
    float qe0 = 0.f, qe1 = 0.f, qe2 = 0.f, qe3 = 0.f;
    #pragma unroll 2
    for (int cg = 0; cg < 96; ++cg) {
        float4 v0 = *(const float4*)&e0[cg * 4];
        float4 v1 = *(const float4*)&e1[cg * 4];
        float4 v2 = *(const float4*)&e2[cg * 4];
        float4 v3 = *(const float4*)&e3[cg * 4];
        float w0 = WqT[(cg * 4 + 0) * D + d];
        float w1 = WqT[(cg * 4 + 1) * D + d];
        float w2 = WqT[(cg * 4 + 2) * D + d];
        float w3 = WqT[(cg * 4 + 3) * D + d];
        const float* f0 = (const float*)&v0;
        const float* f1 = (const float*)&v1;
        const float* f2 = (const float*)&v2;
        const float* f3 = (const float*)&v3;
        float wj[4] = {w0, w1, w2, w3};
        #pragma unroll
        for (int j = 0; j < 4; ++j) {
            qa0 = __builtin_fmaf(f0[j], wj[j], qa0);
            qa1 = __builtin_fmaf(f1[j], wj[j], qa1);
            qa2 = __builtin_fmaf(f2[j], wj[j], qa2);
            qa3 = __builtin_fmaf(f3[j], wj[j], qa3);
        }
    }
    #pragma unroll 2
    for (int cg = 96; cg < 128; ++cg) {
        float4 v0 = *(const float4*)&e0[cg * 4];
        float4 v1 = *(const float4*)&e1[cg * 4];
        float4 v2 = *(const float4*)&e2[cg * 4];
        float4 v3 = *(const float4*)&e3[cg * 4];
        float w0 = WqT[(cg * 4 + 0) * D + d];
        float w1 = WqT[(cg * 4 + 1) * D + d];
        float w2 = WqT[(cg * 4 + 2) * D + d];
        float w3 = WqT[(cg * 4 + 3) * D + d];
        const float* f0 = (const float*)&v0;
        const float* f1 = (const float*)&v1;
        const float* f2 = (const float*)&v2;
        const float* f3 = (const float*)&v3;
        float wj[4] = {w0, w1, w2, w3};
        #pragma unroll
        for (int j = 0; j < 4; ++j) {
            qe0 = __builtin_fmaf(f0[j], wj[j], qe0);
            qe1 = __builtin_fmaf(f1[j], wj[j], qe1);
            qe2 = __builtin_fmaf(f2[j], wj[j], qe2);
            qe3 = __builtin_fmaf(f3[j], wj[j], qe3);
        }
    }
    float bqd = bq[d];
    q32[(size_t)(r0 + 0) * D + d] = (qa0 + qe0) + bqd;
    q32[(size_t)(r0 + 1) * D + d] = (qa1 + qe1) + bqd;
    q32[(size_t)(r0 + 2) * D + d] = (qa2 + qe2) + bqd;
    q32[(size_t)(r0 + 3) * D + d] = (qa3 + qe3) + bqd;
}

// ---------------------------------------------------------------- K2: scores SHADOW via bf16 MFMA
// 64n x 64p tile, 4 waves; wave w: A = Q rows 16w..16w+15, 4 K-frags, k-loop 2x32.
// Shadow-only numerics: bf16 noise sigma ~0.14 << rank-32->40 margin ~2.8.
__global__ __launch_bounds__(256, 4) void k_scores(
    const float* __restrict__ q32, const float* __restrict__ k32,
    _Float16* __restrict__ S16) {
    __shared__ unsigned short sQ[64 * 72];       // [row n][d], pad 72
    __shared__ unsigned short sK[64 * 72];       // [row p][d]
    __shared__ unsigned short sOut[4][16 * 72];  // per-wave repack

    int t  = threadIdx.x;
    int p0 = blockIdx.x * 64;      // 144
    int n0 = blockIdx.y * 64;      // 9
    int b  = blockIdx.z;

    const float* qb = q32 + ((size_t)b * NB + n0) * D;
    const float* kb = k32 + ((size_t)b * HW + p0) * D;

    // stage + fp32->bf16: 1024 float4, 4 per thread
    #pragma unroll
    for (int r = 0; r < 4; ++r) {
        int L = r * 256 + t;
        int row = L >> 4, c4 = L & 15;
        float4 vq = *(const float4*)&qb[(size_t)row * D + c4 * 4];
        float4 vk = *(const float4*)&kb[(size_t)row * D + c4 * 4];
        ushort4 hq, hk;
        hq.x = f2bf(vq.x); hq.y = f2bf(vq.y); hq.z = f2bf(vq.z); hq.w = f2bf(vq.w);
        hk.x = f2bf(vk.x); hk.y = f2bf(vk.y); hk.z = f2bf(vk.z); hk.w = f2bf(vk.w);
        *(ushort4*)&sQ[row * 72 + c4 * 4] = hq;
        *(ushort4*)&sK[row * 72 + c4 * 4] = hk;
    }
    __syncthreads();

    int w = t >> 6, l = t & 63;
    int fr = l & 15;               // frag row (A) / col (B)
    int kb8 = (l >> 4) * 8;        // 8 consecutive k per lane

    f32x4 acc[4] = {f32x4{0,0,0,0}, f32x4{0,0,0,0}, f32x4{0,0,0,0}, f32x4{0,0,0,0}};
    #pragma unroll
    for (int ks = 0; ks < 2; ++ks) {
        bf16x8 a = *(const bf16x8*)&sQ[(16 * w + fr) * 72 + ks * 32 + kb8];
        #pragma unroll
        for (int f = 0; f < 4; ++f) {
            bf16x8 bb = *(const bf16x8*)&sK[(16 * f + fr) * 72 + ks * 32 + kb8];
            acc[f] = __builtin_amdgcn_mfma_f32_16x16x32_bf16(a, bb, acc[f], 0, 0, 0);
        }
    }

    // repack: C/D layout col=lane&15, row=(lane>>4)*4+reg  ->  sOut[w][n_local][p_local]
    unsigned short* so = &sOut[w][0];
    #pragma unroll
    for (int f = 0; f < 4; ++f)
        #pragma unroll
        for (int r = 0; r < 4; ++r) {
            _Float16 h = (_Float16)acc[f][r];
            so[((l >> 4) * 4 + r) * 72 + 16 * f + (l & 15)] = *(unsigned short*)&h;
        }
    __syncthreads();

    // coalesced store: lane -> row l>>2, 16 halfs at col (l&3)*16
    _Float16* Sb = S16 + (size_t)b * NB * HW;
    int orow = l >> 2, oc = (l & 3) * 16;
    uint4 v0 = *(const uint4*)&sOut[w][orow * 72 + oc];
    uint4 v1 = *(const uint4*)&sOut[w][orow * 72 + oc + 8];
    size_t base = (size_t)(n0 + 16 * w + orow) * HW + (p0 + oc);
    *(uint4*)&Sb[base]     = v0;
    *(uint4*)&Sb[base + 8] = v1;
}

// ---------------------------------------------------------------- K3: per-row top-k via 2-pass radix select
__global__ __launch_bounds__(256) void k_topk(
    const _Float16* __restrict__ S16,
    const float* __restrict__ q32, const float* __restrict__ k32,
    int* __restrict__ cidx, float* __restrict__ cval, double* __restrict__ rowss) {
    __shared__ int    hist[4][256];   // per-wave sub-histograms
    __shared__ int    sfx[256];
    __shared__ int    b0s, mAbove, thrS, gcnt;
    __shared__ int    cps[CAP];
    __shared__ float  cv[CAP];
    __shared__ int    cp[CAP];
    __shared__ float  sv[CAP];
    __shared__ int    sp[CAP];
    __shared__ double ssq[TOPK];

    int t   = threadIdx.x;
    int row = blockIdx.x;            // b*NB + n
    int b = row / NB, n = row % NB;
    int wid = t >> 6;

    #pragma unroll
    for (int w = 0; w < 4; ++w) hist[w][t] = 0;
    if (t == 0) gcnt = 0;
    __syncthreads();

    const unsigned short* Srow = (const unsigned short*)(S16 + (size_t)row * HW);
    unsigned int my[36];
    #pragma unroll
    for (int c = 0; c < 9; ++c) {
        ushort4 v4 = ((const ushort4*)Srow)[c * 256 + t];
        #pragma unroll
        for (int j = 0; j < 4; ++j) {
            unsigned int h = (j == 0 ? v4.x : j == 1 ? v4.y : j == 2 ? v4.z : v4.w);
            unsigned int m = (h & 0x8000u) ? (h ^ 0xFFFFu) : (h | 0x8000u);
            int p = (c * 256 + t) * 4 + j;
            int hh = p / W, ww = p - hh * W;
            if (((hh >> 2) * NBH + (ww >> 2)) == n) m = 0;   // self-block mask
            my[c * 4 + j] = m;
            atomicAdd(&hist[wid][m >> 8], 1);
        }
    }
    __syncthreads();

    sfx[t] = hist[0][t] + hist[1][t] + hist[2][t] + hist[3][t];
    __syncthreads();
    #pragma unroll
    for (int off = 1; off < 256; off <<= 1) {
        int v = (t + off < 256) ? sfx[t + off] : 0;
        __syncthreads();
        sfx[t] += v;
        __syncthreads();
    }
    if (sfx[t] >= NCAND && (t == 255 || sfx[t + 1] < NCAND)) {
        b0s = t; mAbove = (t == 255) ? 0 : sfx[t + 1];
    }
    __syncthreads();
    int b0 = b0s, mab = mAbove;
    __syncthreads();

    #pragma unroll
    for (int w = 0; w < 4; ++w) hist[w][t] = 0;
    __syncthreads();
    #pragma unroll
    for (int i = 0; i < 36; ++i)
        if ((int)(my[i] >> 8) == b0) atomicAdd(&hist[wid][my[i] & 255u], 1);
    __syncthreads();
    sfx[t] = hist[0][t] + hist[1][t] + hist[2][t] + hist[3][t];
    __syncthreads();
    #pragma unroll
    for (int off = 1; off < 256; off <<= 1) {
        int v = (t + off < 256) ? sfx[t + off] : 0;
        __syncthreads();
        sfx[t] += v;
        __syncthreads();
    }
    if (mab + sfx[t] >= NCAND && (t == 255 || mab + sfx[t + 1] < NCAND))
        thrS = (b0 << 8) | t;
    __syncthreads();
    unsigned int thr = (unsigned int)thrS;

    #pragma unroll
    for (int i = 0; i < 36; ++i) {
        if (my[i] >= thr) {
            int pos = atomicAdd(&gcnt, 1);
            if (pos < CAP) {
                int c = i >> 2, j = i & 3;
                cps[pos] = (c * 256 + t) * 4 + j;
            }
        }
    }
    __syncthreads();
    int M = min(gcnt, CAP);

    // exact fp32 re-rank — np.einsum SSE order, no FMA (NUMERICS FROZEN)
    if (t < M) {
        #pragma clang fp contract(off)
        int p = cps[t];
        const float* qr = q32 + (size_t)row * D;
        const float* kr = k32 + ((size_t)b * HW + p) * D;
        float L0 = 0.f, L1 = 0.f, L2 = 0.f, L3 = 0.f;
        #pragma unroll
        for (int j = 0; j < 16; ++j) {
            L0 = L0 + qr[4 * j + 0] * kr[4 * j + 0];
            L1 = L1 + qr[4 * j + 1] * kr[4 * j + 1];
            L2 = L2 + qr[4 * j + 2] * kr[4 * j + 2];
            L3 = L3 + qr[4 * j + 3] * kr[4 * j + 3];
        }
        cv[t] = (L0 + L1) + (L2 + L3);
        cp[t] = p;
    }
    __syncthreads();

    if (t < M) {
        float v = cv[t]; int p = cp[t];
        int rank = 0;
        for (int j = 0; j < M; ++j) {
            float vj = cv[j];
            rank += (vj > v) || (vj == v && cp[j] < p);
        }
        sv[rank] = v; sp[rank] = p;
    }
    __syncthreads();

    if (t < TK2) {
        cval[(size_t)row * TK2 + t] = sv[t];
        cidx[(size_t)row * TK2 + t] = sp[t];
    }
    if (t < TOPK) {
        double vi = (double)sv[t], s = 0.0;
        #pragma unroll
        for (int j = 0; j < TK2; ++j) { double dd = vi - (double)sv[j]; s += dd * dd; }
        ssq[t] = s;
    }
    __syncthreads();
    if (t == 0) {
        double s = 0.0;
        #pragma unroll
        for (int i = 0; i < TOPK; ++i) s += ssq[i];
        rowss[row] = s;
    }
}

// ---------------------------------------------------------------- K4: per-batch RMS -> scale
__global__ void k_rms(const double* __restrict__ rowss, double* __restrict__ scale) {
    __shared__ double sb[256];
    int b = blockIdx.x, t = threadIdx.x;
    double s = 0.0;
    for (int r = t; r < NB; r += 256) s += rowss[b * NB + r];
    sb[t] = s; __syncthreads();
    for (int st = 128; st > 0; st >>= 1) {
        if (t < st) sb[t] += sb[t + st];
        __syncthreads();
    }
    if (t == 0) {
        double rms = sqrt(sb[0] / ((double)NB * TOPK * TK2));
        scale[b] = 10.0 / (rms + 1e-3);
    }
}

// ---------------------------------------------------------------- K5: finalize — SOLE writer of d_out (float32)
__global__ __launch_bounds__(256) void k_final(
    const int* __restrict__ cidx, const float* __restrict__ cval,
    const double* __restrict__ scale, float* __restrict__ out) {
    __shared__ double sv[16][TK2];
    int t = threadIdx.x;
    int row0 = blockIdx.x * 16;
    for (int idx = t; idx < 16 * TK2; idx += 256) {
        int r = idx >> 5, j = idx & 31;
        sv[r][j] = (double)cval[(size_t)(row0 + r) * TK2 + j];
    }
    __syncthreads();
    int r = t >> 4, i = t & 15;
    int row = row0 + r;
    double scb = scale[row / NB];
    double vi = sv[r][i];
    double s = 0.0;
    #pragma unroll
    for (int j = 0; j < TK2; ++j) {
        double x = (vi - sv[r][j]) * scb;
        s += 1.0 / (1.0 + exp(-x));
    }
    out[(size_t)B * NB * TOPK + (size_t)row * TOPK + i] = (float)tanh(s - (double)TOPK);
    out[(size_t)row * TOPK + i] = (float)cidx[(size_t)row * TK2 + i];
}

// ---------------------------------------------------------------- sentinel fill (ws too small)
__global__ void k_fill(float* out, int nelem) {
    int i = blockIdx.x * 256 + threadIdx.x;
    if (i < nelem) out[i] = -12345.0f;
}

// ---------------------------------------------------------------- launch
extern "C" void kernel_launch(void* const* d_in, const int* in_sizes, int n_in,
                              void* d_out, int out_size, void* d_ws, size_t ws_size,
                              hipStream_t stream) {
    const float* src = (const float*)d_in[0];
    const float* Wq  = (const float*)d_in[1];
    const float* bq  = (const float*)d_in[2];
    const float* Wk  = (const float*)d_in[3];
    const float* bk  = (const float*)d_in[4];
    float* out = (float*)d_out;

    char* ws = (char*)d_ws;
    size_t oWkT = 0;
    size_t oWqT = oWkT + (size_t)C * D * 4;
    size_t oQ   = oWqT + (size_t)C * D * 4;
    size_t oK   = oQ   + (size_t)B * NB * D * 4;
    size_t oS   = oK   + (size_t)B * HW * D * 4;
    size_t oEmb = oS   + (size_t)B * NB * HW * 2;
    size_t oCV  = oEmb + (size_t)B * NB * C * 4;
    size_t oCI  = oCV  + (size_t)B * NB * TK2 * 4;
    size_t oRS  = oCI  + (size_t)B * NB * TK2 * 4;
    size_t oSc  = oRS  + (size_t)B * NB * 8;
    size_t need = oSc  + (size_t)B * 8;

    if (ws_size < need) {
        k_fill<<<(out_size + 255) / 256, 256, 0, stream>>>(out, out_size);
        return;
    }

    float*     WkT  = (float*)(ws + oWkT);
    float*     WqT  = (float*)(ws + oWqT);
    float*     q32  = (float*)(ws + oQ);
    float*     k32  = (float*)(ws + oK);
    _Float16*  S16  = (_Float16*)(ws + oS);
    float*     emb  = (float*)(ws + oEmb);
    float*     cval = (float*)(ws + oCV);
    int*       cidx = (int*)(ws + oCI);
    double*    rss  = (double*)(ws + oRS);
    double*    scl  = (double*)(ws + oSc);

    k_transpose<<<(C * D + 255) / 256, 256, 0, stream>>>(Wk, Wq, WkT, WqT);
    k_embed<<<B * NB, 256, 0, stream>>>(src, WkT, bk, k32, emb);
    k_q<<<B * NB / 16, 256, 0, stream>>>(emb, WqT, bq, q32);
    k_scores<<<dim3(HW / 64, NB / 64, B), 256, 0, stream>>>(q32, k32, S16);
    k_topk<<<B * NB, 256, 0, stream>>>(S16, q32, k32, cidx, cval, rss);
    k_rms<<<B, 256, 0, stream>>>(rss, scl);
    k_final<<<B * NB / 16, 256, 0, stream>>>(cidx, cval, scl, out);
}